// Round 4
// baseline (1434.947 us; speedup 1.0000x reference)
//
#include <hip/hip_runtime.h>

typedef unsigned short u16;

#define NWG 256
#define NT  256
#define TS  512
#define HD  1024
#define BS  128
#define NI  64
#define NO  64
#define XR  16      // batch rows per XCD
#define CC  32      // hidden cols per CU
#define RCP 17      // redC padded row stride

typedef __attribute__((ext_vector_type(8))) short bf16x8;
typedef __attribute__((ext_vector_type(4))) float f32x4;

__device__ __forceinline__ float bf2f(u16 u) {
    union { unsigned int i; float f; } v; v.i = ((unsigned int)u) << 16; return v.f;
}
__device__ __forceinline__ u16 f2bf(float f) {
    union { float fl; unsigned int i; } v; v.fl = f;
    unsigned int x = v.i;
    return (u16)((x + 0x7fffu + ((x >> 16) & 1u)) >> 16);  // RNE, finite inputs
}
__device__ __forceinline__ float ldv(const void* p, size_t i, bool isf32) {
    return isf32 ? ((const float*)p)[i] : bf2f(((const u16*)p)[i]);
}

// L2-executed atomic returning old value (sc0 = return-old).
// ROUND-3 POST-MORTEM (hang): flag POLLS must be atomics. A plain sc0-load
// spinning on a peer CU's store does NOT promptly observe it (round-6
// finding); the sc0-load data path works only because it runs AFTER an
// atomic flag observation established ordering. Round-1 showed the converse
// (plain-store publish + atomic poll) bounces lines L2<->memory (+240MB HBM
// writes). The ONLY proven transport is atomic publish + atomic poll.
__device__ __forceinline__ unsigned l2_atomic_add(unsigned* p, unsigned v) {
    unsigned old;
    asm volatile("global_atomic_add %0, %1, %2, off sc0\n\t"
                 "s_waitcnt vmcnt(0)"
                 : "=&v"(old) : "v"(p), "v"(v) : "memory");
    return old;
}
// Fire-and-forget atomic SWAP publish (no return, no wait). Single writer per
// word => no RMW accumulation at the coherence point.
__device__ __forceinline__ void l2_atomic_swap_nr(unsigned* p, unsigned v) {
    asm volatile("global_atomic_swap %0, %1, off" :: "v"(p), "v"(v) : "memory");
}

// 8 A-fragments (one K-quarter) via sc0 loads (L1 bypass -> XCD L2, where peer
// CUs' write-through stores live). Proven correct for *data* across sessions.
__device__ __forceinline__ void load_a_frags(const u16* ap, bf16x8* a) {
    asm volatile(
        "global_load_dwordx4 %0, %8, off sc0\n\t"
        "global_load_dwordx4 %1, %8, off offset:64 sc0\n\t"
        "global_load_dwordx4 %2, %8, off offset:128 sc0\n\t"
        "global_load_dwordx4 %3, %8, off offset:192 sc0\n\t"
        "global_load_dwordx4 %4, %8, off offset:256 sc0\n\t"
        "global_load_dwordx4 %5, %8, off offset:320 sc0\n\t"
        "global_load_dwordx4 %6, %8, off offset:384 sc0\n\t"
        "global_load_dwordx4 %7, %8, off offset:448 sc0\n\t"
        "s_waitcnt vmcnt(0)"
        : "=&v"(a[0]), "=&v"(a[1]), "=&v"(a[2]), "=&v"(a[3]),
          "=&v"(a[4]), "=&v"(a[5]), "=&v"(a[6]), "=&v"(a[7])
        : "v"(ap) : "memory");
}

// Mailbox layout: mb[xcd][consumer(32)][wave(4)][producer(8)] u32: each
// (consumer,wave) owns a private 64B line with the flags of the 8 producers
// its K-quarter depends on (wave w <- slots 8w..8w+7). Producer slot s
// publishes h_t by swapping (t+1) into word mb[c][s>>3][s&7] for every
// consumer c. value v >= t+1 <=> h_t published. WAR safety of the h ping-pong:
// a CU stores h_{t+1} only after all its waves (joined at the redC barrier)
// observed h_t from all 32 producers, and producing h_t implies that producer
// finished reading h_{t-1}. (Round-2 transport, proven at 1417us.)
#define MBL 16      // u32 words per (consumer,wave) line (64B)

// LDS ~157KB -> exactly 1 WG/CU (required by the per-XCD ticket scheme).
__global__ __launch_bounds__(NT)
void arnn_xcd(const void* __restrict__ xv,
              const void* __restrict__ encwv,
              const void* __restrict__ encbv,
              const void* __restrict__ recwv,
              const void* __restrict__ fgtwv,
              const void* __restrict__ decwv,
              const void* __restrict__ decbv,
              const void* __restrict__ hinitwv,
              const void* __restrict__ hinitbv,
              void* __restrict__ outv,
              u16* __restrict__ h0buf,
              u16* __restrict__ h1buf,
              unsigned* __restrict__ tickets,
              unsigned* __restrict__ mboxes)
{
    // WB: staging for register fragment pull (also pins LDS -> 1 WG/CU).
    __shared__ short WB[132 * 64 * 8];          // 135168 B
    __shared__ float redC[4 * 5 * 16 * RCP];    // 21760 B: [kq][tile(4=dec)][row][col]
    __shared__ unsigned s_xcd, s_slot;
    __shared__ int s_f32;

    const int tid  = threadIdx.x;
    const int wave = tid >> 6;
    const int lane = tid & 63;
    const int m    = lane & 15;      // C row / A row (batch-local)
    const int quad = lane >> 4;      // k-subblock within K=32

    // ---- identify XCD, claim per-XCD CU slot ----
    if (tid == 0) {
        unsigned xcc;
        asm volatile("s_getreg_b32 %0, hwreg(HW_REG_XCC_ID, 0, 4)" : "=s"(xcc));
        xcc &= 7u;
        unsigned slot = l2_atomic_add(tickets + xcc * 16, 1u);
        s_xcd = xcc;
        s_slot = slot & 31u;
        s_f32 = 0;
    }
    __syncthreads();
    { // runtime dtype detection on rec_w raw bits (round-1 post-mortem)
        float v = bf2f(((const u16*)recwv)[tid]);
        if (!(v >= -1.0f && v <= 1.0f)) s_f32 = 1;
    }
    __syncthreads();
    const bool isf32 = (s_f32 != 0);
    const int xcd  = (int)s_xcd;
    const int slot = (int)s_slot;
    const int b0   = xcd * XR;       // this XCD's batch rows
    const int j0   = slot * CC;      // this CU's hidden cols
    const int dt   = slot & 3;       // dec tile: out cols 16dt..16dt+15
    const int rg   = slot >> 2;      // dec row-group: rows 2rg..2rg+1 (balanced decode)
    unsigned* mbX   = mboxes + (size_t)xcd * 32 * 4 * MBL;      // XCD's flag block
    unsigned* mbW   = mbX + (slot * 4 + wave) * MBL;            // this wave's 8 flags
    // producer-side publish target word (per consumer c, computed in loop):
    const int pw = (slot >> 3), pi = (slot & 7);

    // ---- stage weights into LDS in B-frag order ----
    for (int idx = tid; idx < 132 * 64; idx += NT) {
        int ksg = idx >> 6, l = idx & 63, n = l & 15, q = l >> 4;
        int tile, ksl;
        if (ksg < 34)       { tile = 0; ksl = ksg; }
        else if (ksg < 68)  { tile = 1; ksl = ksg - 34; }
        else if (ksg < 100) { tile = 2; ksl = ksg - 68; }
        else                { tile = 3; ksl = ksg - 100; }
        int j = j0 + ((tile & 1) << 4) + n;
        bf16x8 v;
        if (!isf32) {
            const u16* src;
            if (tile < 2) src = (ksl < 32) ? (const u16*)recwv + (size_t)j * HD + ksl * 32 + q * 8
                                           : (const u16*)encwv + (size_t)j * NI + (ksl - 32) * 32 + q * 8;
            else          src = (const u16*)fgtwv + (size_t)j * HD + ksl * 32 + q * 8;
            v = *(const bf16x8*)src;
        } else {
            const float* src;
            if (tile < 2) src = (ksl < 32) ? (const float*)recwv + (size_t)j * HD + ksl * 32 + q * 8
                                           : (const float*)encwv + (size_t)j * NI + (ksl - 32) * 32 + q * 8;
            else          src = (const float*)fgtwv + (size_t)j * HD + ksl * 32 + q * 8;
            #pragma unroll
            for (int i = 0; i < 8; ++i) v[i] = (short)f2bf(src[i]);
        }
        *(bf16x8*)&WB[idx * 8] = v;
    }
    __syncthreads();     // WB fully staged before register pull

    // ---- ALL B-fragments register-resident (1 wave/SIMD -> big VGPR budget).
    bf16x8 Breg[2][8];   // rec tiles 0,1 for this wave's K-quarter
    bf16x8 Freg[2][8];   // fgt tiles 2,3 for this wave's K-quarter
    #pragma unroll
    for (int ks = 0; ks < 8; ++ks) {
        int kb = wave * 8 + ks;
        Breg[0][ks] = *(const bf16x8*)&WB[((0   + kb) * 64 + lane) * 8];
        Breg[1][ks] = *(const bf16x8*)&WB[((34  + kb) * 64 + lane) * 8];
        Freg[0][ks] = *(const bf16x8*)&WB[((68  + kb) * 64 + lane) * 8];
        Freg[1][ks] = *(const bf16x8*)&WB[((100 + kb) * 64 + lane) * 8];
    }
    bf16x8 Ereg[2];      // enc-tail B-frags (waves 0,1 only)
    if (wave < 2) {
        Ereg[0] = *(const bf16x8*)&WB[((32 + wave) * 64 + lane) * 8];
        Ereg[1] = *(const bf16x8*)&WB[((34 + 32 + wave) * 64 + lane) * 8];
    }
    bf16x8 dfr[8];       // dec B-frags for this wave's K-quarter
    {
        int o = 16 * dt + m;         // out column
        #pragma unroll
        for (int ks = 0; ks < 8; ++ks) {
            int kb = wave * 256 + ks * 32 + quad * 8;
            if (!isf32) dfr[ks] = *(const bf16x8*)((const u16*)decwv + (size_t)o * HD + kb);
            else {
                const float* src = (const float*)decwv + (size_t)o * HD + kb;
                #pragma unroll
                for (int i = 0; i < 8; ++i) dfr[ks][i] = (short)f2bf(src[i]);
            }
        }
    }
    // per-thread scalars; h state in registers. Paired-column mapping: thread
    // owns (row er2, cols ec2/ec2+1) -> h stores become ONE packed dword
    // (halves store count, coalesces lines, shrinks the pre-publish drain).
    const int er2 = tid >> 4, ec2 = (tid & 15) * 2;          // 16 rows x 16 col-pairs
    float encb0 = ldv(encbv, j0 + ec2,     isf32);
    float encb1 = ldv(encbv, j0 + ec2 + 1, isf32);
    float decb_r = ldv(decbv, 16 * dt + (tid & 15), isf32);
    float hstA = ldv(hinitwv, j0 + ec2,     isf32) + ldv(hinitbv, j0 + ec2,     isf32);
    float hstB = ldv(hinitwv, j0 + ec2 + 1, isf32) + ldv(hinitbv, j0 + ec2 + 1, isf32);
    {
        unsigned pack = (unsigned)f2bf(hstA) | ((unsigned)f2bf(hstB) << 16);
        *(unsigned*)&h0buf[(size_t)(b0 + er2) * HD + j0 + ec2] = pack;
    }
    __syncthreads();                             // h0 stores acked by L2 (vmcnt(0))
    if (tid < 32)                                // publish h_0: value 1
        l2_atomic_swap_nr(mbX + (tid * 4 + pw) * MBL + pi, 1u);

    // x prefetch registers (one step ahead; covers the compulsory HBM miss
    // with the following step's MFMA/elementwise/drain instead of stalling)
    bf16x8 xpB = {};
    f32x4 xr0 = {}, xr1 = {};
    if (wave < 2) {
        size_t xb = (size_t)(b0 + m) * (TS * NI) + (size_t)0 * NI + wave * 32 + quad * 8;
        if (!isf32) xpB = *(const bf16x8*)((const u16*)xv + xb);
        else { const float* xp = (const float*)xv + xb;
               xr0 = *(const f32x4*)xp; xr1 = *(const f32x4*)(xp + 4); }
    }

    // ---- recurrence ----
    for (int t = 0; t < TS; ++t) {
        f32x4 acc[5];
        #pragma unroll
        for (int tt = 0; tt < 5; ++tt) acc[tt] = (f32x4){0.f, 0.f, 0.f, 0.f};

        // enc contribution BEFORE the wait (x was prefetched last iteration)
        if (wave < 2) {
            bf16x8 xf;
            if (!isf32) xf = xpB;
            else {
                #pragma unroll
                for (int i = 0; i < 4; ++i) {
                    xf[i]     = (short)f2bf(xr0[i]);
                    xf[i + 4] = (short)f2bf(xr1[i]);
                }
            }
            acc[0] = __builtin_amdgcn_mfma_f32_16x16x32_bf16(xf, Ereg[0], acc[0], 0, 0, 0);
            acc[1] = __builtin_amdgcn_mfma_f32_16x16x32_bf16(xf, Ereg[1], acc[1], 0, 0, 0);
        }

        // Per-wave poll: one 8-lane ATOMIC gather of this wave's OWN producer
        // flags (private 64B line; proven round-2 transport).
        {
            const unsigned target = (unsigned)(t + 1);
            for (;;) {
                unsigned v = target;
                if (lane < 8) v = l2_atomic_add(mbW + lane, 0u);
                if (__all((int)(v >= target))) break;
            }
        }

        const u16* cur = (t & 1) ? h1buf : h0buf;
        u16*       nxt = (t & 1) ? h0buf : h1buf;

        bf16x8 a[8];
        load_a_frags(cur + (size_t)(b0 + m) * HD + wave * 256 + quad * 8, a);

        // issue next step's x prefetch now (vmcnt-clean point; consumed at
        // next iteration's enc-MFMA)
        if (wave < 2) {
            int tn = (t + 1 < TS) ? t + 1 : t;
            size_t xb = (size_t)(b0 + m) * (TS * NI) + (size_t)tn * NI + wave * 32 + quad * 8;
            if (!isf32) xpB = *(const bf16x8*)((const u16*)xv + xb);
            else { const float* xp = (const float*)xv + xb;
                   xr0 = *(const f32x4*)xp; xr1 = *(const f32x4*)(xp + 4); }
        }

        #pragma unroll
        for (int ks = 0; ks < 8; ++ks) {
            acc[0] = __builtin_amdgcn_mfma_f32_16x16x32_bf16(a[ks], Breg[0][ks], acc[0], 0, 0, 0);
            acc[1] = __builtin_amdgcn_mfma_f32_16x16x32_bf16(a[ks], Breg[1][ks], acc[1], 0, 0, 0);
            acc[2] = __builtin_amdgcn_mfma_f32_16x16x32_bf16(a[ks], Freg[0][ks], acc[2], 0, 0, 0);
            acc[3] = __builtin_amdgcn_mfma_f32_16x16x32_bf16(a[ks], Freg[1][ks], acc[3], 0, 0, 0);
            acc[4] = __builtin_amdgcn_mfma_f32_16x16x32_bf16(a[ks], dfr[ks],     acc[4], 0, 0, 0);
        }

        // C-layout 16x16: col = lane&15, row = quad*4 + reg
        #pragma unroll
        for (int tt = 0; tt < 5; ++tt) {
            #pragma unroll
            for (int r = 0; r < 4; ++r)
                redC[((wave * 5 + tt) * 16 + quad * 4 + r) * RCP + m] = acc[tt][r];
        }
        __syncthreads();

        // elementwise (h stores issue early; one packed dword per thread)
        {
            const int tl = ec2 >> 4, c0 = ec2 & 15;
            float pr0 = encb0, pf0 = 0.f, pr1 = encb1, pf1 = 0.f;
            #pragma unroll
            for (int kq = 0; kq < 4; ++kq) {
                pr0 += redC[((kq * 5 + tl) * 16 + er2) * RCP + c0];
                pf0 += redC[((kq * 5 + 2 + tl) * 16 + er2) * RCP + c0];
                pr1 += redC[((kq * 5 + tl) * 16 + er2) * RCP + c0 + 1];
                pf1 += redC[((kq * 5 + 2 + tl) * 16 + er2) * RCP + c0 + 1];
            }
            float fg0 = 1.0f / (1.0f + __expf(-pf0));
            float hn0 = pr0 / (1.0f + fabsf(pr0));
            hstA = hstA + fg0 * (hn0 - hstA);
            float fg1 = 1.0f / (1.0f + __expf(-pf1));
            float hn1 = pr1 / (1.0f + fabsf(pr1));
            hstB = hstB + fg1 * (hn1 - hstB);
            unsigned pack = (unsigned)f2bf(hstA) | ((unsigned)f2bf(hstB) << 16);
            *(unsigned*)&nxt[(size_t)(b0 + er2) * HD + j0 + ec2] = pack;
        }
        // BALANCED decode: every slot handles 2 rows (rg) x 16 cols (dt) of
        // out -- redC reads buffered to REGISTERS before barrier2 (WAR-safe),
        // the global store issues AFTER the publish (off the critical path).
        float dec_o = 0.f;
        int dr = 0;
        if (tid < 32) {
            dr = 2 * rg + (tid >> 4);            // out row (batch-local)
            int col = tid & 15;
            dec_o = decb_r;
            #pragma unroll
            for (int kq = 0; kq < 4; ++kq)
                dec_o += redC[((kq * 5 + 4) * 16 + dr) * RCP + col];
        }
        __syncthreads();                       // all waves' h stores acked by L2
        if (tid < 32)                          // publish h_{t+1}: value t+2
            l2_atomic_swap_nr(mbX + (tid * 4 + pw) * MBL + pi, (unsigned)(t + 2));
        if (tid < 32 && t > 0) {               // out[t-1] store, post-publish
            size_t oi = (size_t)(t - 1) * (BS * NO) + (size_t)(b0 + dr) * NO + 16 * dt + (tid & 15);
            if (isf32) ((float*)outv)[oi] = dec_o; else ((u16*)outv)[oi] = f2bf(dec_o);
        }
    }

    // ---- epilogue: out[511] = decode(h_512); final hidden ----
    {
        {   // per-wave poll for h_512 (value TS+1) -- all slots participate now
            const unsigned target = (unsigned)(TS + 1);
            for (;;) {
                unsigned v = target;
                if (lane < 8) v = l2_atomic_add(mbW + lane, 0u);
                if (__all((int)(v >= target))) break;
            }
        }
        bf16x8 a[8];
        load_a_frags(h0buf + (size_t)(b0 + m) * HD + wave * 256 + quad * 8, a);
        f32x4 ac = (f32x4){0.f, 0.f, 0.f, 0.f};
        #pragma unroll
        for (int ks = 0; ks < 8; ++ks)
            ac = __builtin_amdgcn_mfma_f32_16x16x32_bf16(a[ks], dfr[ks], ac, 0, 0, 0);
        #pragma unroll
        for (int r = 0; r < 4; ++r)
            redC[((wave * 5 + 4) * 16 + quad * 4 + r) * RCP + m] = ac[r];
        __syncthreads();
        if (tid < 32) {   // balanced decode of step 511
            int dr = 2 * rg + (tid >> 4), col = tid & 15;
            float o = decb_r;
            #pragma unroll
            for (int kq = 0; kq < 4; ++kq)
                o += redC[((kq * 5 + 4) * 16 + dr) * RCP + col];
            size_t oi = (size_t)511 * (BS * NO) + (size_t)(b0 + dr) * NO + 16 * dt + col;
            if (isf32) ((float*)outv)[oi] = o; else ((u16*)outv)[oi] = f2bf(o);
        }
    }
    {   // final hidden straight from registers (paired columns)
        size_t oi = (size_t)TS * BS * NO + (size_t)(b0 + er2) * HD + j0 + ec2;
        if (isf32) { ((float*)outv)[oi] = hstA; ((float*)outv)[oi + 1] = hstB; }
        else {
            unsigned pack = (unsigned)f2bf(hstA) | ((unsigned)f2bf(hstB) << 16);
            *(unsigned*)&((u16*)outv)[oi] = pack;
        }
    }
}

extern "C" void kernel_launch(void* const* d_in, const int* in_sizes, int n_in,
                              void* d_out, int out_size, void* d_ws, size_t ws_size,
                              hipStream_t stream) {
    (void)in_sizes; (void)n_in; (void)out_size; (void)ws_size;
    const void* xv       = d_in[0];
    const void* encwv    = d_in[1];
    const void* encbv    = d_in[2];
    const void* recwv    = d_in[3];
    const void* fgtwv    = d_in[4];
    const void* decwv    = d_in[5];
    const void* decbv    = d_in[6];
    const void* hinitwv  = d_in[7];
    const void* hinitbv  = d_in[8];
    void* outv = d_out;

    unsigned* tickets = (unsigned*)d_ws;                       // 8 x 64B-stride
    unsigned* mboxes  = (unsigned*)((char*)d_ws + 4096);       // 8 x 32 x 4 x 64B = 64KB
    u16* h0buf = (u16*)((char*)d_ws + 524288);
    u16* h1buf = h0buf + (size_t)BS * HD;

    // zero tickets + mailboxes each launch (ws is re-poisoned to 0xAA)
    hipMemsetAsync(d_ws, 0, 4096 + 8 * 32 * 4 * MBL * 4, stream);

    void* args[] = { (void*)&xv, (void*)&encwv, (void*)&encbv, (void*)&recwv,
                     (void*)&fgtwv, (void*)&decwv, (void*)&decbv,
                     (void*)&hinitwv, (void*)&hinitbv,
                     (void*)&outv, (void*)&h0buf, (void*)&h1buf,
                     (void*)&tickets, (void*)&mboxes };
    // Round-8 lesson: NEVER ignore the cooperative-launch return code.
    hipError_t err = hipLaunchCooperativeKernel((void*)arnn_xcd, dim3(NWG), dim3(NT), args, 0, stream);
    if (err != hipSuccess) {
        hipLaunchKernelGGL(arnn_xcd, dim3(NWG), dim3(NT), 0, stream,
                           xv, encwv, encbv, recwv, fgtwv, decwv, decbv,
                           hinitwv, hinitbv, outv, h0buf, h1buf, tickets, mboxes);
    }
}